// Round 1
// baseline (418.357 us; speedup 1.0000x reference)
//
#include <hip/hip_runtime.h>

// ---------------------------------------------------------------------------
// SparseGRUBrain: N=70000 neurons, H=8, E=1.12M edges, B=8.
// Strategy: build CSR (by tgt) in workspace each call, then one fused kernel
// does sparse-input accumulation + GRU + projection per (neuron, batch) pair.
// Workspace layout:
//   [0, 4N)            : cnt / cursor (int)
//   [512KiB, ...)      : rowPtr (N+1 ints)
//   [1MiB, 1MiB+8E)    : elist (int2: {edge id, src[e]}) in CSR order
// ---------------------------------------------------------------------------

__device__ __forceinline__ float fast_sigmoid(float x) {
    return 1.0f / (1.0f + __expf(-x));
}
__device__ __forceinline__ float fast_tanh(float x) {
    return 2.0f / (1.0f + __expf(-2.0f * x)) - 1.0f;
}

#define LOAD8(dst, ptr)                                                        \
    {                                                                          \
        const float4* _p = (const float4*)(ptr);                               \
        float4 _a = _p[0], _b = _p[1];                                         \
        dst[0] = _a.x; dst[1] = _a.y; dst[2] = _a.z; dst[3] = _a.w;            \
        dst[4] = _b.x; dst[5] = _b.y; dst[6] = _b.z; dst[7] = _b.w;            \
    }

#define FMA8(acc, ptr, s)                                                      \
    {                                                                          \
        const float4* _p = (const float4*)(ptr);                               \
        float4 _a = _p[0], _b = _p[1];                                         \
        acc[0] += _a.x * (s); acc[1] += _a.y * (s);                            \
        acc[2] += _a.z * (s); acc[3] += _a.w * (s);                            \
        acc[4] += _b.x * (s); acc[5] += _b.y * (s);                            \
        acc[6] += _b.z * (s); acc[7] += _b.w * (s);                            \
    }

__global__ void hist_kernel(const int* __restrict__ tgt, int* __restrict__ cnt, int E) {
    int i = blockIdx.x * blockDim.x + threadIdx.x;
    if (i < E) atomicAdd(&cnt[tgt[i]], 1);
}

// Single-block exclusive scan over N counts. cnt is read then overwritten in
// place with the cursor (start offset); rowPtr gets the exclusive scan + total.
__global__ void scan_kernel(int* cnt, int* __restrict__ rowPtr, int N) {
    __shared__ int lds[1024];
    const int t = threadIdx.x;
    const int chunk = (N + 1023) >> 10;
    const int s0 = t * chunk;
    const int s1 = min(s0 + chunk, N);
    int sum = 0;
    for (int i = s0; i < s1; ++i) sum += cnt[i];
    lds[t] = sum;
    __syncthreads();
    for (int off = 1; off < 1024; off <<= 1) {
        int v = (t >= off) ? lds[t - off] : 0;
        __syncthreads();
        lds[t] += v;
        __syncthreads();
    }
    int prefix = (t == 0) ? 0 : lds[t - 1];
    int total = lds[1023];
    for (int i = s0; i < s1; ++i) {
        int c = cnt[i];
        rowPtr[i] = prefix;
        cnt[i] = prefix;  // cursor init
        prefix += c;
    }
    if (t == 0) rowPtr[N] = total;
}

__global__ void scatter_kernel(const int* __restrict__ src, const int* __restrict__ tgt,
                               int* __restrict__ cursor, int2* __restrict__ elist, int E) {
    int i = blockIdx.x * blockDim.x + threadIdx.x;
    if (i < E) {
        int pos = atomicAdd(&cursor[tgt[i]], 1);
        elist[pos] = make_int2(i, src[i]);
    }
}

// Fused main kernel: one thread per (neuron, batch). Block = 32 neurons x 8 b.
// Lanes 8k..8k+7 share a neuron -> W/U/bias loads broadcast within the wave.
__global__ __launch_bounds__(256) void gru_main(
    const float* __restrict__ calcium, const float* __restrict__ hidden,
    const float* __restrict__ Wz, const float* __restrict__ Wr, const float* __restrict__ Wh,
    const float* __restrict__ Uz, const float* __restrict__ Ur, const float* __restrict__ Uh,
    const float* __restrict__ bz, const float* __restrict__ br, const float* __restrict__ bh,
    const float* __restrict__ proj,
    const int* __restrict__ rowPtr, const int2* __restrict__ elist,
    float* __restrict__ outCal, float* __restrict__ outHid, int N) {
    const int tid = threadIdx.x;
    const int n = blockIdx.x * 32 + (tid >> 3);
    const int b = tid & 7;
    if (n >= N) return;

    float az[8], ar[8], ah[8];
    LOAD8(az, bz + (size_t)n * 8);
    LOAD8(ar, br + (size_t)n * 8);
    LOAD8(ah, bh + (size_t)n * 8);

    // ---- sparse input accumulation over this neuron's edges ----
    const int start = rowPtr[n];
    const int end = rowPtr[n + 1];
    const float* calB = calcium + (size_t)b * N;
    for (int j = start; j < end; ++j) {
        int2 es = elist[j];
        float c = calB[es.y];
        size_t w = (size_t)es.x * 8;
        FMA8(az, Wz + w, c);
        FMA8(ar, Wr + w, c);
        FMA8(ah, Wh + w, c);
    }

    // ---- dense GRU ----
    float hv[8];
    LOAD8(hv, hidden + ((size_t)b * N + n) * 8);

    float rz[8] = {0, 0, 0, 0, 0, 0, 0, 0};
    float rr[8] = {0, 0, 0, 0, 0, 0, 0, 0};
    const float* uz = Uz + (size_t)n * 64;
    const float* ur = Ur + (size_t)n * 64;
#pragma unroll
    for (int hh = 0; hh < 8; ++hh) {
        FMA8(rz, uz + hh * 8, hv[hh]);
        FMA8(rr, ur + hh * 8, hv[hh]);
    }

    float z[8], r[8], rh[8];
#pragma unroll
    for (int i = 0; i < 8; ++i) {
        z[i] = fast_sigmoid(az[i] + rz[i]);
        r[i] = fast_sigmoid(ar[i] + rr[i]);
        rh[i] = r[i] * hv[i];
    }

    const float* uh = Uh + (size_t)n * 64;
#pragma unroll
    for (int hh = 0; hh < 8; ++hh) {
        FMA8(ah, uh + hh * 8, rh[hh]);
    }

    float pj[8];
    LOAD8(pj, proj);

    float hn[8];
    float cal = 0.0f;
#pragma unroll
    for (int i = 0; i < 8; ++i) {
        float ht = fast_tanh(ah[i]);
        hn[i] = (1.0f - z[i]) * hv[i] + z[i] * ht;
        cal += hn[i] * pj[i];
    }

    float4* oh = (float4*)(outHid + ((size_t)b * N + n) * 8);
    oh[0] = make_float4(hn[0], hn[1], hn[2], hn[3]);
    oh[1] = make_float4(hn[4], hn[5], hn[6], hn[7]);
    outCal[(size_t)b * N + n] = fmaxf(cal, 0.0f);
}

extern "C" void kernel_launch(void* const* d_in, const int* in_sizes, int n_in,
                              void* d_out, int out_size, void* d_ws, size_t ws_size,
                              hipStream_t stream) {
    const float* calcium = (const float*)d_in[0];
    const float* hidden  = (const float*)d_in[1];
    const int*   src     = (const int*)d_in[2];
    const int*   tgt     = (const int*)d_in[3];
    const float* Wz      = (const float*)d_in[4];
    const float* Wr      = (const float*)d_in[5];
    const float* Wh      = (const float*)d_in[6];
    const float* Uz      = (const float*)d_in[7];
    const float* Ur      = (const float*)d_in[8];
    const float* Uh      = (const float*)d_in[9];
    const float* bz      = (const float*)d_in[10];
    const float* br      = (const float*)d_in[11];
    const float* bh      = (const float*)d_in[12];
    const float* proj    = (const float*)d_in[13];

    const int E = in_sizes[2];
    const int H = in_sizes[13];           // 8
    const int N = in_sizes[10] / H;       // 70000
    const int B = in_sizes[0] / N;        // 8
    (void)B; (void)n_in; (void)out_size; (void)ws_size;

    float* out = (float*)d_out;
    float* outCal = out;
    float* outHid = out + (size_t)in_sizes[0];  // after (B,N) calcium block

    char* ws = (char*)d_ws;
    int*  cursor = (int*)ws;                      // N ints (cnt, then cursor)
    int*  rowPtr = (int*)(ws + 512 * 1024);       // N+1 ints
    int2* elist  = (int2*)(ws + 1024 * 1024);     // E int2

    hipMemsetAsync(cursor, 0, (size_t)N * sizeof(int), stream);

    hist_kernel<<<(E + 255) / 256, 256, 0, stream>>>(tgt, cursor, E);
    scan_kernel<<<1, 1024, 0, stream>>>(cursor, rowPtr, N);
    scatter_kernel<<<(E + 255) / 256, 256, 0, stream>>>(src, tgt, cursor, elist, E);
    gru_main<<<(N + 31) / 32, 256, 0, stream>>>(
        calcium, hidden, Wz, Wr, Wh, Uz, Ur, Uh, bz, br, bh, proj,
        rowPtr, elist, outCal, outHid, N);
}

// Round 2
// 289.618 us; speedup vs baseline: 1.4445x; 1.4445x over previous
//
#include <hip/hip_runtime.h>

// ---------------------------------------------------------------------------
// SparseGRUBrain: N=70000, H=8, E=1.12M, B=8.
// CSR-by-tgt rebuilt each call (rank from hist atomics, no scatter atomics),
// rows padded to multiples of 4 edges; pad entries {e=0, s=N} hit a zero
// column in the transposed calcium table -> contribute 0.
// Main kernel: thread = (neuron, batch); 4-edge unrolled loop for MLP/ILP.
// ---------------------------------------------------------------------------

__device__ __forceinline__ float fast_sigmoid(float x) {
    return 1.0f / (1.0f + __expf(-x));
}
__device__ __forceinline__ float fast_tanh(float x) {
    return 2.0f / (1.0f + __expf(-2.0f * x)) - 1.0f;
}

#define LOAD8(dst, ptr)                                                        \
    {                                                                          \
        const float4* _p = (const float4*)(ptr);                               \
        float4 _a = _p[0], _b = _p[1];                                         \
        dst[0] = _a.x; dst[1] = _a.y; dst[2] = _a.z; dst[3] = _a.w;            \
        dst[4] = _b.x; dst[5] = _b.y; dst[6] = _b.z; dst[7] = _b.w;            \
    }

#define FMA8(acc, ptr, s)                                                      \
    {                                                                          \
        const float4* _p = (const float4*)(ptr);                               \
        float4 _a = _p[0], _b = _p[1];                                         \
        acc[0] += _a.x * (s); acc[1] += _a.y * (s);                            \
        acc[2] += _a.z * (s); acc[3] += _a.w * (s);                            \
        acc[4] += _b.x * (s); acc[5] += _b.y * (s);                            \
        acc[6] += _b.z * (s); acc[7] += _b.w * (s);                            \
    }

// cnt[t]++ per edge; the atomic's return value is this edge's rank in bucket.
__global__ void hist_kernel(const int* __restrict__ tgt, int* __restrict__ cnt,
                            int* __restrict__ rank, int E) {
    int i = blockIdx.x * blockDim.x + threadIdx.x;
    int base = i * 4;
    if (base + 3 < E) {
        int4 t = *(const int4*)(tgt + base);
        rank[base + 0] = atomicAdd(&cnt[t.x], 1);
        rank[base + 1] = atomicAdd(&cnt[t.y], 1);
        rank[base + 2] = atomicAdd(&cnt[t.z], 1);
        rank[base + 3] = atomicAdd(&cnt[t.w], 1);
    } else {
        for (int k = base; k < E; ++k) rank[k] = atomicAdd(&cnt[tgt[k]], 1);
    }
}

// Single-block exclusive scan of PADDED counts (ceil(cnt/4)*4).
__global__ void scan_kernel(const int* __restrict__ cnt, int* __restrict__ rowPtr, int N) {
    __shared__ int lds[1024];
    const int t = threadIdx.x;
    const int chunk = (N + 1023) >> 10;
    const int s0 = t * chunk;
    const int s1 = min(s0 + chunk, N);
    int sum = 0;
    for (int i = s0; i < s1; ++i) sum += (cnt[i] + 3) & ~3;
    lds[t] = sum;
    __syncthreads();
    for (int off = 1; off < 1024; off <<= 1) {
        int v = (t >= off) ? lds[t - off] : 0;
        __syncthreads();
        lds[t] += v;
        __syncthreads();
    }
    int prefix = (t == 0) ? 0 : lds[t - 1];
    int total = lds[1023];
    for (int i = s0; i < s1; ++i) {
        rowPtr[i] = prefix;
        prefix += (cnt[i] + 3) & ~3;
    }
    if (t == 0) rowPtr[N] = total;
}

// Pre-fill elist with pad entries {e=0, s=N} (s=N -> calT row of zeros).
__global__ void fill_kernel(int4* __restrict__ elist2, int total2, int N) {
    int i = blockIdx.x * blockDim.x + threadIdx.x;
    if (i < total2) elist2[i] = make_int4(0, N, 0, N);
}

// calT[(N+1) x 8]: calT[n*8+b] = calcium[b*N+n]; row N = zeros.
__global__ void caltrans_kernel(const float* __restrict__ cal, float* __restrict__ calT,
                                int N) {
    int n = blockIdx.x * blockDim.x + threadIdx.x;
    if (n > N) return;
    float v[8];
    if (n < N) {
#pragma unroll
        for (int b = 0; b < 8; ++b) v[b] = cal[(size_t)b * N + n];
    } else {
#pragma unroll
        for (int b = 0; b < 8; ++b) v[b] = 0.0f;
    }
    float4* o = (float4*)(calT + (size_t)n * 8);
    o[0] = make_float4(v[0], v[1], v[2], v[3]);
    o[1] = make_float4(v[4], v[5], v[6], v[7]);
}

// No atomics: position = rowPtr[tgt] + rank.
__global__ void scatter_kernel(const int* __restrict__ src, const int* __restrict__ tgt,
                               const int* __restrict__ rank, const int* __restrict__ rowPtr,
                               int2* __restrict__ elist, int E) {
    int i = blockIdx.x * blockDim.x + threadIdx.x;
    if (i < E) {
        int t = tgt[i];
        elist[rowPtr[t] + rank[i]] = make_int2(i, src[i]);
    }
}

// Fused main: thread = (neuron, batch). Block = 32 neurons x 8 batches.
// Lanes 8k..8k+7 share a neuron -> W/U/bias/elist loads broadcast in-wave.
__global__ __launch_bounds__(256) void gru_main(
    const float* __restrict__ calT, const float* __restrict__ hidden,
    const float* __restrict__ Wz, const float* __restrict__ Wr, const float* __restrict__ Wh,
    const float* __restrict__ Uz, const float* __restrict__ Ur, const float* __restrict__ Uh,
    const float* __restrict__ bz, const float* __restrict__ br, const float* __restrict__ bh,
    const float* __restrict__ proj,
    const int* __restrict__ rowPtr, const int2* __restrict__ elist,
    float* __restrict__ outCal, float* __restrict__ outHid, int N) {
    const int tid = threadIdx.x;
    const int n = blockIdx.x * 32 + (tid >> 3);
    const int b = tid & 7;
    if (n >= N) return;

    float az[8], ar[8], ah[8];
    LOAD8(az, bz + (size_t)n * 8);
    LOAD8(ar, br + (size_t)n * 8);
    LOAD8(ah, bh + (size_t)n * 8);

    // ---- sparse input accumulation: 4 independent edges per iteration ----
    const int start = rowPtr[n];
    const int nIter = (rowPtr[n + 1] - start) >> 2;
    const int4* ep = (const int4*)(elist + start);
    for (int it = 0; it < nIter; ++it) {
        int4 p0 = ep[2 * it];       // {e0, s0, e1, s1}
        int4 p1 = ep[2 * it + 1];   // {e2, s2, e3, s3}
        float c0 = calT[(size_t)p0.y * 8 + b];
        float c1 = calT[(size_t)p0.w * 8 + b];
        float c2 = calT[(size_t)p1.y * 8 + b];
        float c3 = calT[(size_t)p1.w * 8 + b];
        size_t w0 = (size_t)p0.x * 8, w1 = (size_t)p0.z * 8;
        size_t w2 = (size_t)p1.x * 8, w3 = (size_t)p1.z * 8;
        FMA8(az, Wz + w0, c0); FMA8(ar, Wr + w0, c0); FMA8(ah, Wh + w0, c0);
        FMA8(az, Wz + w1, c1); FMA8(ar, Wr + w1, c1); FMA8(ah, Wh + w1, c1);
        FMA8(az, Wz + w2, c2); FMA8(ar, Wr + w2, c2); FMA8(ah, Wh + w2, c2);
        FMA8(az, Wz + w3, c3); FMA8(ar, Wr + w3, c3); FMA8(ah, Wh + w3, c3);
    }

    // ---- dense GRU ----
    float hv[8];
    LOAD8(hv, hidden + ((size_t)b * N + n) * 8);

    float rz[8] = {0, 0, 0, 0, 0, 0, 0, 0};
    float rr[8] = {0, 0, 0, 0, 0, 0, 0, 0};
    const float* uz = Uz + (size_t)n * 64;
    const float* ur = Ur + (size_t)n * 64;
#pragma unroll
    for (int hh = 0; hh < 8; ++hh) {
        FMA8(rz, uz + hh * 8, hv[hh]);
        FMA8(rr, ur + hh * 8, hv[hh]);
    }

    float z[8], r[8], rh[8];
#pragma unroll
    for (int i = 0; i < 8; ++i) {
        z[i] = fast_sigmoid(az[i] + rz[i]);
        r[i] = fast_sigmoid(ar[i] + rr[i]);
        rh[i] = r[i] * hv[i];
    }

    const float* uh = Uh + (size_t)n * 64;
#pragma unroll
    for (int hh = 0; hh < 8; ++hh) {
        FMA8(ah, uh + hh * 8, rh[hh]);
    }

    float pj[8];
    LOAD8(pj, proj);

    float hn[8];
    float cal = 0.0f;
#pragma unroll
    for (int i = 0; i < 8; ++i) {
        float ht = fast_tanh(ah[i]);
        hn[i] = (1.0f - z[i]) * hv[i] + z[i] * ht;
        cal += hn[i] * pj[i];
    }

    float4* oh = (float4*)(outHid + ((size_t)b * N + n) * 8);
    oh[0] = make_float4(hn[0], hn[1], hn[2], hn[3]);
    oh[1] = make_float4(hn[4], hn[5], hn[6], hn[7]);
    outCal[(size_t)b * N + n] = fmaxf(cal, 0.0f);
}

extern "C" void kernel_launch(void* const* d_in, const int* in_sizes, int n_in,
                              void* d_out, int out_size, void* d_ws, size_t ws_size,
                              hipStream_t stream) {
    const float* calcium = (const float*)d_in[0];
    const float* hidden  = (const float*)d_in[1];
    const int*   src     = (const int*)d_in[2];
    const int*   tgt     = (const int*)d_in[3];
    const float* Wz      = (const float*)d_in[4];
    const float* Wr      = (const float*)d_in[5];
    const float* Wh      = (const float*)d_in[6];
    const float* Uz      = (const float*)d_in[7];
    const float* Ur      = (const float*)d_in[8];
    const float* Uh      = (const float*)d_in[9];
    const float* bz      = (const float*)d_in[10];
    const float* br      = (const float*)d_in[11];
    const float* bh      = (const float*)d_in[12];
    const float* proj    = (const float*)d_in[13];

    const int E = in_sizes[2];
    const int H = in_sizes[13];           // 8
    const int N = in_sizes[10] / H;       // 70000
    (void)n_in; (void)out_size; (void)ws_size;

    float* out = (float*)d_out;
    float* outCal = out;
    float* outHid = out + (size_t)in_sizes[0];

    // workspace layout (bytes):
    //   [0,            4N)        cnt
    //   [512K,         512K+4N+4) rowPtr
    //   [1M,           1M+32(N+1)) calT
    //   [4M,           4M+4E)     rank
    //   [9M,           9M+8*(E+3N)) elist (padded CSR)
    char* ws = (char*)d_ws;
    int*   cnt    = (int*)ws;
    int*   rowPtr = (int*)(ws + (512 << 10));
    float* calT   = (float*)(ws + (1 << 20));
    int*   rank   = (int*)(ws + (4 << 20));
    int2*  elist  = (int2*)(ws + (9 << 20));

    const int padMax = E + 3 * N;  // max padded entries

    hipMemsetAsync(cnt, 0, (size_t)N * sizeof(int), stream);
    hist_kernel<<<(E / 4 + 256) / 256, 256, 0, stream>>>(tgt, cnt, rank, E);
    scan_kernel<<<1, 1024, 0, stream>>>(cnt, rowPtr, N);
    {
        int total2 = (padMax + 1) / 2;
        fill_kernel<<<(total2 + 255) / 256, 256, 0, stream>>>((int4*)elist, total2, N);
    }
    caltrans_kernel<<<(N + 256) / 256, 256, 0, stream>>>(calcium, calT, N);
    scatter_kernel<<<(E + 255) / 256, 256, 0, stream>>>(src, tgt, rank, rowPtr, elist, E);
    gru_main<<<(N + 31) / 32, 256, 0, stream>>>(
        calT, hidden, Wz, Wr, Wh, Uz, Ur, Uh, bz, br, bh, proj,
        rowPtr, elist, outCal, outHid, N);
}

// Round 3
// 289.562 us; speedup vs baseline: 1.4448x; 1.0002x over previous
//
#include <hip/hip_runtime.h>

// ---------------------------------------------------------------------------
// SparseGRUBrain: N=70000, H=8, E=1.12M, B=8.
// CSR-by-tgt rebuilt each call. Rows padded to multiples of 8 with
// {e=0, src=N} (calT row N is zero -> contributes nothing).
// Main kernel: ONE WAVE PER NEURON, lane = (slot s, batch b) = 8x8.
//   - edge loop: lane s handles edges s, s+8, ... (8x MLP vs thread-serial)
//   - dense einsums: lane (s,b) computes the h=s partial, then a 3-round
//     __shfl_xor butterfly over the slot dim reduces everything.
// ---------------------------------------------------------------------------

__device__ __forceinline__ float fast_sigmoid(float x) {
    return 1.0f / (1.0f + __expf(-x));
}
__device__ __forceinline__ float fast_tanh(float x) {
    return 2.0f / (1.0f + __expf(-2.0f * x)) - 1.0f;
}

#define LOAD8(dst, ptr)                                                        \
    {                                                                          \
        const float4* _p = (const float4*)(ptr);                               \
        float4 _a = _p[0], _b = _p[1];                                         \
        dst[0] = _a.x; dst[1] = _a.y; dst[2] = _a.z; dst[3] = _a.w;            \
        dst[4] = _b.x; dst[5] = _b.y; dst[6] = _b.z; dst[7] = _b.w;            \
    }

#define FMA8(acc, ptr, s)                                                      \
    {                                                                          \
        const float4* _p = (const float4*)(ptr);                               \
        float4 _a = _p[0], _b = _p[1];                                         \
        acc[0] += _a.x * (s); acc[1] += _a.y * (s);                            \
        acc[2] += _a.z * (s); acc[3] += _a.w * (s);                            \
        acc[4] += _b.x * (s); acc[5] += _b.y * (s);                            \
        acc[6] += _b.z * (s); acc[7] += _b.w * (s);                            \
    }

// cnt[t]++ per edge; atomic return value = this edge's rank within bucket.
__global__ void hist_kernel(const int* __restrict__ tgt, int* __restrict__ cnt,
                            int* __restrict__ rank, int E) {
    int i = blockIdx.x * blockDim.x + threadIdx.x;
    int base = i * 4;
    if (base + 3 < E) {
        int4 t = *(const int4*)(tgt + base);
        rank[base + 0] = atomicAdd(&cnt[t.x], 1);
        rank[base + 1] = atomicAdd(&cnt[t.y], 1);
        rank[base + 2] = atomicAdd(&cnt[t.z], 1);
        rank[base + 3] = atomicAdd(&cnt[t.w], 1);
    } else {
        for (int k = base; k < E; ++k) rank[k] = atomicAdd(&cnt[tgt[k]], 1);
    }
}

// Single-block exclusive scan of counts padded to multiples of 8.
__global__ void scan_kernel(const int* __restrict__ cnt, int* __restrict__ rowPtr, int N) {
    __shared__ int lds[1024];
    const int t = threadIdx.x;
    const int chunk = ((N + 1023) >> 10 | 3) + 1;  // round chunk up to mult of 4
    const int s0 = t * chunk;
    const int s1 = min(s0 + chunk, N);
    int sum = 0;
    int i = s0;
    for (; i + 3 < s1; i += 4) {
        int4 v = *(const int4*)(cnt + i);
        sum += ((v.x + 7) & ~7) + ((v.y + 7) & ~7) + ((v.z + 7) & ~7) + ((v.w + 7) & ~7);
    }
    for (; i < s1; ++i) sum += (cnt[i] + 7) & ~7;
    lds[t] = sum;
    __syncthreads();
    for (int off = 1; off < 1024; off <<= 1) {
        int v = (t >= off) ? lds[t - off] : 0;
        __syncthreads();
        lds[t] += v;
        __syncthreads();
    }
    int prefix = (t == 0) ? 0 : lds[t - 1];
    int total = lds[1023];
    for (i = s0; i < s1; ++i) {
        rowPtr[i] = prefix;
        prefix += (cnt[i] + 7) & ~7;
    }
    if (t == 0) rowPtr[N] = total;
}

// Fused N-wide prep: calcium transpose (+ zero row N) and pad-slot fill.
__global__ void prep_n(const float* __restrict__ cal, float* __restrict__ calT,
                       const int* __restrict__ cnt, const int* __restrict__ rowPtr,
                       int2* __restrict__ elist, int N) {
    int n = blockIdx.x * blockDim.x + threadIdx.x;
    if (n > N) return;
    float4* o = (float4*)(calT + (size_t)n * 8);
    if (n == N) {
        o[0] = make_float4(0.f, 0.f, 0.f, 0.f);
        o[1] = make_float4(0.f, 0.f, 0.f, 0.f);
        return;
    }
    float v[8];
#pragma unroll
    for (int b = 0; b < 8; ++b) v[b] = cal[(size_t)b * N + n];
    o[0] = make_float4(v[0], v[1], v[2], v[3]);
    o[1] = make_float4(v[4], v[5], v[6], v[7]);
    // pad fill: slots [cnt, padded) get {e=0, src=N}
    int c = cnt[n];
    int p = rowPtr[n];
    int padded = (c + 7) & ~7;
    for (int j = c; j < padded; ++j) elist[p + j] = make_int2(0, N);
}

// No atomics: position = rowPtr[tgt] + rank.
__global__ void scatter_kernel(const int* __restrict__ src, const int* __restrict__ tgt,
                               const int* __restrict__ rank, const int* __restrict__ rowPtr,
                               int2* __restrict__ elist, int E) {
    int i = blockIdx.x * blockDim.x + threadIdx.x;
    if (i < E) {
        int t = tgt[i];
        elist[rowPtr[t] + rank[i]] = make_int2(i, src[i]);
    }
}

// Main: one wave per neuron. lane = s*8 + b (s = edge slot / h index, b = batch).
__global__ __launch_bounds__(256) void gru_main(
    const float* __restrict__ calT, const float* __restrict__ hidden,
    const float* __restrict__ Wz, const float* __restrict__ Wr, const float* __restrict__ Wh,
    const float* __restrict__ Uz, const float* __restrict__ Ur, const float* __restrict__ Uh,
    const float* __restrict__ bz, const float* __restrict__ br, const float* __restrict__ bh,
    const float* __restrict__ proj,
    const int* __restrict__ rowPtr, const int2* __restrict__ elist,
    float* __restrict__ outCal, float* __restrict__ outHid, int N) {
    const int lane = threadIdx.x & 63;
    const int n = blockIdx.x * 4 + (threadIdx.x >> 6);
    if (n >= N) return;
    const int s = lane >> 3;  // slot / h index
    const int b = lane & 7;   // batch

    float az[8] = {0, 0, 0, 0, 0, 0, 0, 0};
    float ar[8] = {0, 0, 0, 0, 0, 0, 0, 0};
    float ah[8] = {0, 0, 0, 0, 0, 0, 0, 0};

    // ---- sparse input partials: lane s takes edges s, s+8, ... (uniform trips)
    const int start = rowPtr[n];
    const int end = rowPtr[n + 1];
#pragma unroll 2
    for (int j = start + s; j < end; j += 8) {
        int2 es = elist[j];
        float c = calT[(size_t)es.y * 8 + b];
        size_t w = (size_t)es.x * 8;
        FMA8(az, Wz + w, c);
        FMA8(ar, Wr + w, c);
        FMA8(ah, Wh + w, c);
    }

    // ---- dense partials for h = s ----
    float hv[8];
    LOAD8(hv, hidden + ((size_t)b * N + n) * 8);
    const size_t u = (size_t)n * 64 + s * 8;
    FMA8(az, Uz + u, hv[s]);
    FMA8(ar, Ur + u, hv[s]);

    // ---- butterfly reduce az, ar over slot dim ----
#pragma unroll
    for (int m = 8; m <= 32; m <<= 1) {
#pragma unroll
        for (int i = 0; i < 8; ++i) {
            az[i] += __shfl_xor(az[i], m, 64);
            ar[i] += __shfl_xor(ar[i], m, 64);
        }
    }

    float bzv[8], brv[8];
    LOAD8(bzv, bz + (size_t)n * 8);
    LOAD8(brv, br + (size_t)n * 8);
    float z[8], r[8];
#pragma unroll
    for (int i = 0; i < 8; ++i) {
        z[i] = fast_sigmoid(az[i] + bzv[i]);
        r[i] = fast_sigmoid(ar[i] + brv[i]);
    }

    // ---- recurrent h partial for h = s, then reduce ----
    FMA8(ah, Uh + u, r[s] * hv[s]);
#pragma unroll
    for (int m = 8; m <= 32; m <<= 1) {
#pragma unroll
        for (int i = 0; i < 8; ++i) ah[i] += __shfl_xor(ah[i], m, 64);
    }

    float bhv[8], pj[8];
    LOAD8(bhv, bh + (size_t)n * 8);
    LOAD8(pj, proj);

    float hn[8];
    float cal = 0.0f;
#pragma unroll
    for (int i = 0; i < 8; ++i) {
        float ht = fast_tanh(ah[i] + bhv[i]);
        hn[i] = (1.0f - z[i]) * hv[i] + z[i] * ht;
        cal += hn[i] * pj[i];
    }

    if (s == 0) {
        float4* oh = (float4*)(outHid + ((size_t)b * N + n) * 8);
        oh[0] = make_float4(hn[0], hn[1], hn[2], hn[3]);
        oh[1] = make_float4(hn[4], hn[5], hn[6], hn[7]);
        outCal[(size_t)b * N + n] = fmaxf(cal, 0.0f);
    }
}

extern "C" void kernel_launch(void* const* d_in, const int* in_sizes, int n_in,
                              void* d_out, int out_size, void* d_ws, size_t ws_size,
                              hipStream_t stream) {
    const float* calcium = (const float*)d_in[0];
    const float* hidden  = (const float*)d_in[1];
    const int*   src     = (const int*)d_in[2];
    const int*   tgt     = (const int*)d_in[3];
    const float* Wz      = (const float*)d_in[4];
    const float* Wr      = (const float*)d_in[5];
    const float* Wh      = (const float*)d_in[6];
    const float* Uz      = (const float*)d_in[7];
    const float* Ur      = (const float*)d_in[8];
    const float* Uh      = (const float*)d_in[9];
    const float* bz      = (const float*)d_in[10];
    const float* br      = (const float*)d_in[11];
    const float* bh      = (const float*)d_in[12];
    const float* proj    = (const float*)d_in[13];

    const int E = in_sizes[2];
    const int H = in_sizes[13];           // 8
    const int N = in_sizes[10] / H;       // 70000
    (void)n_in; (void)out_size; (void)ws_size;

    float* out = (float*)d_out;
    float* outCal = out;
    float* outHid = out + (size_t)in_sizes[0];

    // workspace (bytes):
    //   [0,    280K)   cnt
    //   [512K, 792K)   rowPtr
    //   [1M,   3.3M)   calT (N+1 rows x 8 f32)
    //   [3.5M, 8M)     rank
    //   [8M,   ~21M)   elist (padded CSR, int2)
    char* ws = (char*)d_ws;
    int*   cnt    = (int*)ws;
    int*   rowPtr = (int*)(ws + (512 << 10));
    float* calT   = (float*)(ws + (1 << 20));
    int*   rank   = (int*)(ws + (3584 << 10));
    int2*  elist  = (int2*)(ws + (8 << 20));

    hipMemsetAsync(cnt, 0, (size_t)N * sizeof(int), stream);
    hist_kernel<<<((E + 3) / 4 + 255) / 256, 256, 0, stream>>>(tgt, cnt, rank, E);
    scan_kernel<<<1, 1024, 0, stream>>>(cnt, rowPtr, N);
    prep_n<<<(N + 256) / 256, 256, 0, stream>>>(calcium, calT, cnt, rowPtr, elist, N);
    scatter_kernel<<<(E + 255) / 256, 256, 0, stream>>>(src, tgt, rank, rowPtr, elist, E);
    gru_main<<<(N + 3) / 4, 256, 0, stream>>>(
        calT, hidden, Wz, Wr, Wh, Uz, Ur, Uh, bz, br, bh, proj,
        rowPtr, elist, outCal, outHid, N);
}